// Round 6
// baseline (288.199 us; speedup 1.0000x reference)
//
#include <hip/hip_runtime.h>
#include <math.h>

#define NB 4
#define DD 128
#define HH 128
#define WW 128
#define VOX (DD*HH*WW)          // 2097152 = 2^21
#define NVOX (NB*VOX)           // 8388608
#define ROLL 8

struct GaussW { float w[7]; };

__device__ __forceinline__ float4 f4zero() { float4 z; z.x = z.y = z.z = z.w = 0.f; return z; }

// ---------------------------------------------------------------------------
// 7-tap 1D conv along z, float4 along x, rolled 8 in z.
// launch_bounds(256,4): VGPR cap 128 (ring alone is 56) -- prevents the
// allocator's default 8-wave heuristic (64 VGPR) from spilling the ring.
template <int SHIFT>
__global__ __launch_bounds__(256, 4)
void smooth_roll4_kernel(const float* __restrict__ in, float* __restrict__ out,
                         GaussW gw) {
    int t = blockIdx.x * blockDim.x + threadIdx.x;
    int xq   = t & 31;            // x0 = 4*xq
    int cblk = (t >> 5) & 15;     // conv-axis 8-block
    int rest = t >> 9;
    int oc   = rest & 127;        // other axis coordinate
    int n    = rest >> 7;
    int c0   = cblk * ROLL;
    const int OSHIFT = (SHIFT == 14) ? 7 : 14;
    size_t base = ((size_t)n << 21) | ((size_t)oc << OSHIFT) | ((size_t)(xq << 2));

    float4 r[ROLL + 6];
#pragma unroll
    for (int j = 0; j < ROLL + 6; ++j) {
        int cc = c0 - 3 + j;
        r[j] = (cc >= 0 && cc < 128)
             ? *(const float4*)(in + base + ((size_t)cc << SHIFT))
             : f4zero();
    }
#pragma unroll
    for (int i = 0; i < ROLL; ++i) {
        float4 a = f4zero();
#pragma unroll
        for (int k = 0; k < 7; ++k) {
            float wk = gw.w[k];
            a.x += wk * r[i + k].x;
            a.y += wk * r[i + k].y;
            a.z += wk * r[i + k].z;
            a.w += wk * r[i + k].w;
        }
        *(float4*)(out + base + ((size_t)(c0 + i) << SHIFT)) = a;
    }
}

// ---------------------------------------------------------------------------
// |curl| of one float4 at (n fixed via u/vv/w, z, y, x0). Same math as R5.
__device__ __forceinline__ float4 curl4_at(const float* __restrict__ u,
                                           const float* __restrict__ vv,
                                           const float* __restrict__ w,
                                           int z, int y, int x0, int xq) {
    size_t s = ((size_t)z << 14) | ((size_t)y << 7) | (size_t)x0;
    int dy = (y < 127) ? 128 : -128;
    int dz = (z < 127) ? 16384 : -16384;
    float sy = (y < 127) ? 1.f : -1.f;
    float sz = (z < 127) ? 1.f : -1.f;
    int dxp = (xq < 31) ? 4 : 0;

    const float4 wc  = *(const float4*)(w  + s);
    const float4 wyn = *(const float4*)(w  + s + dy);
    const float4 vc  = *(const float4*)(vv + s);
    const float4 vzn = *(const float4*)(vv + s + dz);
    const float4 uc  = *(const float4*)(u  + s);
    const float4 uzn = *(const float4*)(u  + s + dz);
    const float4 uyn = *(const float4*)(u  + s + dy);
    const float  wxp = w [s + 3 + dxp];
    const float  vxp = vv[s + 3 + dxp];

    float wca[4] = {wc.x, wc.y, wc.z, wc.w};
    float vca[4] = {vc.x, vc.y, vc.z, vc.w};
    float wya[4] = {wyn.x, wyn.y, wyn.z, wyn.w};
    float vza[4] = {vzn.x, vzn.y, vzn.z, vzn.w};
    float uca[4] = {uc.x, uc.y, uc.z, uc.w};
    float uza[4] = {uzn.x, uzn.y, uzn.z, uzn.w};
    float uya[4] = {uyn.x, uyn.y, uyn.z, uyn.w};
    float wsh[4] = {wc.y, wc.z, wc.w, wxp};
    float vsh[4] = {vc.y, vc.z, vc.w, vxp};

    float4 o;
    float* oa = &o.x;
#pragma unroll
    for (int j = 0; j < 4; ++j) {
        int x = x0 + j;
        float fdxw = (x < 127) ? (wsh[j] - wca[j]) : (wca[3] - wca[2]);
        float fdxv = (x < 127) ? (vsh[j] - vca[j]) : (vca[3] - vca[2]);
        float fdyw = sy * (wya[j] - wca[j]);
        float fdyu = sy * (uya[j] - uca[j]);
        float fdzv = sz * (vza[j] - vca[j]);
        float fdzu = sz * (uza[j] - uca[j]);
        float cu = fdyw - fdzv;
        float cv = fdzu - fdxw;
        float cw = fdxv - fdyu;
        oa[j] = sqrtf(cu * cu + cv * cv + cw * cw);
    }
    return o;
}

// Fused |curl(v)| + z-smooth, float4 x-vector, 8-z ring.
// launch_bounds(256,2): VGPR cap 256 (~115 needed) -- the R3 version of this
// kernel spilled because the default heuristic capped it at 64 VGPR.
__global__ __launch_bounds__(256, 2)
void curl_zsmooth4_kernel(const float* __restrict__ v, float* __restrict__ vn,
                          GaussW gw) {
    int idx = blockIdx.x * blockDim.x + threadIdx.x;  // 2^18 threads
    int xq = idx & 31;
    int y  = (idx >> 5) & 127;
    int zb = (idx >> 12) & 15;
    int n  = idx >> 16;
    int x0 = xq << 2;
    int z0 = zb * 8;
    const float* u  = v + (size_t)n * 3 * VOX;
    const float* vv = u + VOX;
    const float* w  = vv + VOX;

    float4 r[8 + 6];
#pragma unroll
    for (int jj = 0; jj < 14; ++jj) {
        int zz = z0 - 3 + jj;
        r[jj] = (zz >= 0 && zz < 128) ? curl4_at(u, vv, w, zz, y, x0, xq) : f4zero();
    }
#pragma unroll
    for (int i = 0; i < 8; ++i) {
        float4 a = f4zero();
#pragma unroll
        for (int k = 0; k < 7; ++k) {
            float wk = gw.w[k];
            a.x += wk * r[i + k].x;
            a.y += wk * r[i + k].y;
            a.z += wk * r[i + k].z;
            a.w += wk * r[i + k].w;
        }
        *(float4*)(vn + (((size_t)n << 21) | ((size_t)(z0 + i) << 14) | ((size_t)y << 7) | (size_t)x0)) = a;
    }
}

// ---------------------------------------------------------------------------
// Fused y-conv + x-conv for one (n, z, y-quarter) slab. float4 throughout.
// LDS: in_t 19.0 KB + mid 17.0 KB = 36 KB -> 4 blocks/CU.
__global__ void yx_smooth4_kernel(const float* __restrict__ in, float* __restrict__ out,
                                  GaussW gw) {
    __shared__ float in_t[38][128];    // y0-3 .. y0+34
    __shared__ float mid[32][136];     // col = x+4; cols 0-3 & 132-135 are zero halo

    int b  = blockIdx.x;               // NB*DD*4 = 2048
    int yq = b & 3;
    int z  = (b >> 2) & 127;
    int n  = b >> 9;
    int y0 = yq * 32;
    size_t slice = (((size_t)n << 7) | (size_t)z) << 14;
    int tid = threadIdx.x;

    // stage 38 rows (float4, zero-padded in y)
    for (int j = tid; j < 38 * 32; j += 256) {
        int r  = j >> 5;
        int c4 = (j & 31) << 2;
        int gy = y0 - 3 + r;
        float4 val = (gy >= 0 && gy < 128)
                   ? *(const float4*)(in + slice + ((size_t)gy << 7) + c4)
                   : f4zero();
        *(float4*)&in_t[r][c4] = val;
    }
    __syncthreads();

    // zero x-halo of mid
    if (tid < 32) {
        *(float4*)&mid[tid][0]   = f4zero();
        *(float4*)&mid[tid][132] = f4zero();
    }
    // y-conv -> mid
    for (int j = tid; j < 32 * 32; j += 256) {
        int yo = j >> 5;
        int c4 = (j & 31) << 2;
        float4 a = f4zero();
#pragma unroll
        for (int k = 0; k < 7; ++k) {
            float wk = gw.w[k];
            float4 t = *(const float4*)&in_t[yo + k][c4];
            a.x += wk * t.x; a.y += wk * t.y; a.z += wk * t.z; a.w += wk * t.w;
        }
        *(float4*)&mid[yo][c4 + 4] = a;
    }
    __syncthreads();

    // x-conv -> global
    for (int j = tid; j < 32 * 32; j += 256) {
        int yo  = j >> 5;
        int x0c = (j & 31) << 2;
        float4 m0 = *(const float4*)&mid[yo][x0c];
        float4 m1 = *(const float4*)&mid[yo][x0c + 4];
        float4 m2 = *(const float4*)&mid[yo][x0c + 8];
        float wdw[12] = {m0.x, m0.y, m0.z, m0.w,
                         m1.x, m1.y, m1.z, m1.w,
                         m2.x, m2.y, m2.z, m2.w};
        float o[4];
#pragma unroll
        for (int j2 = 0; j2 < 4; ++j2) {
            float acc = 0.f;
#pragma unroll
            for (int k = 0; k < 7; ++k) acc += gw.w[k] * wdw[j2 + 1 + k];
            o[j2] = acc;
        }
        *(float4*)(out + slice + ((size_t)(y0 + yo) << 7) + x0c) =
            make_float4(o[0], o[1], o[2], o[3]);
    }
}

// ---------------------------------------------------------------------------
// Render: per (n,y,x) column, flip z, cumsum -> transmittance, trapezoid, clip.
#define RBATCH 16
__global__ void render_kernel(const float* __restrict__ ds, const float* __restrict__ vn,
                              float* __restrict__ out) {
    int idx = blockIdx.x * blockDim.x + threadIdx.x;  // NB*HH*WW = 65536
    if (idx >= NB * HH * WW) return;
    int x = idx & 127;
    int y = (idx >> 7) & 127;
    int n = idx >> 14;
    size_t volbase = (size_t)n * VOX + ((size_t)y << 7) + x;

    float xacc = 0.f, acc = 0.f, tp = 0.f, vp = 0.f;
    for (int b = 0; b < 128 / RBATCH; ++b) {
        float rds[RBATCH], rvn[RBATCH];
#pragma unroll
        for (int i = 0; i < RBATCH; ++i) {
            int z = 127 - (b * RBATCH + i);
            size_t off = volbase + ((size_t)z << 14);
            rds[i] = ds[off];
            rvn[i] = vn[off];
        }
#pragma unroll
        for (int i = 0; i < RBATCH; ++i) {
            int k = b * RBATCH + i;
            xacc += rds[i];
            float xc = 20.f * xacc;
            float tk = (xc + 1.f) * expf(-xc);
            float vk = rvn[i];
            if (k == 0) acc = (1.f - tk) * vk;
            else        acc += (tp - tk) * (vp + vk) * 0.5f;
            tp = tk; vp = vk;
        }
    }
    out[idx] = fminf(fmaxf(acc, 0.f), 1.f);
}

// ---------------------------------------------------------------------------
extern "C" void kernel_launch(void* const* d_in, const int* in_sizes, int n_in,
                              void* d_out, int out_size, void* d_ws, size_t ws_size,
                              hipStream_t stream) {
    const float* d = (const float*)d_in[0];   // (4,1,128,128,128)
    const float* v = (const float*)d_in[1];   // (4,3,128,128,128)
    float* out = (float*)d_out;               // (4,1,128,128)

    GaussW gw;
    {
        double g[7], s = 0.0;
        for (int i = 0; i < 7; ++i) {
            double t = (i - 3) / 1.6;
            g[i] = exp(-t * t / 2.0);
            s += g[i];
        }
        for (int i = 0; i < 7; ++i) gw.w[i] = (float)(g[i] / s);
    }

    float* ws0 = (float*)d_ws;        // ds final
    float* ws1 = ws0 + NVOX;          // intermediates
    float* ws2 = ws1 + NVOX;          // vn final

    const int TB = 256;

    // vn chain: fused curl+z-smooth, then fused y+x
    curl_zsmooth4_kernel<<<(1 << 18) / TB, TB, 0, stream>>>(v, ws1, gw);
    yx_smooth4_kernel<<<NB * DD * 4, TB, 0, stream>>>(ws1, ws2, gw);

    // ds chain: z-smooth (register ring), then fused y+x
    smooth_roll4_kernel<14><<<(NVOX / 32) / TB, TB, 0, stream>>>(d, ws1, gw);
    yx_smooth4_kernel<<<NB * DD * 4, TB, 0, stream>>>(ws1, ws0, gw);

    // final render reduction
    render_kernel<<<(NB * HH * WW) / TB, TB, 0, stream>>>(ws0, ws2, out);
}

// Round 7
// 238.316 us; speedup vs baseline: 1.2093x; 1.2093x over previous
//
#include <hip/hip_runtime.h>
#include <math.h>

#define NB 4
#define DD 128
#define HH 128
#define WW 128
#define VOX (DD*HH*WW)          // 2097152 = 2^21
#define NVOX (NB*VOX)           // 8388608
#define ROLL 8

struct GaussW { float w[7]; };

__device__ __forceinline__ float4 f4zero() { float4 z; z.x = z.y = z.z = z.w = 0.f; return z; }

// ---------------------------------------------------------------------------
// 7-tap 1D conv along z, float4 along x, rolled 8 in z.
template <int SHIFT>
__global__ __launch_bounds__(256, 4)
void smooth_roll4_kernel(const float* __restrict__ in, float* __restrict__ out,
                         GaussW gw) {
    int t = blockIdx.x * blockDim.x + threadIdx.x;
    int xq   = t & 31;            // x0 = 4*xq
    int cblk = (t >> 5) & 15;     // conv-axis 8-block
    int rest = t >> 9;
    int oc   = rest & 127;        // other axis coordinate
    int n    = rest >> 7;
    int c0   = cblk * ROLL;
    const int OSHIFT = (SHIFT == 14) ? 7 : 14;
    size_t base = ((size_t)n << 21) | ((size_t)oc << OSHIFT) | ((size_t)(xq << 2));

    float4 r[ROLL + 6];
#pragma unroll
    for (int j = 0; j < ROLL + 6; ++j) {
        int cc = c0 - 3 + j;
        r[j] = (cc >= 0 && cc < 128)
             ? *(const float4*)(in + base + ((size_t)cc << SHIFT))
             : f4zero();
    }
#pragma unroll
    for (int i = 0; i < ROLL; ++i) {
        float4 a = f4zero();
#pragma unroll
        for (int k = 0; k < 7; ++k) {
            float wk = gw.w[k];
            a.x += wk * r[i + k].x;
            a.y += wk * r[i + k].y;
            a.z += wk * r[i + k].z;
            a.w += wk * r[i + k].w;
        }
        *(float4*)(out + base + ((size_t)(c0 + i) << SHIFT)) = a;
    }
}

// ---------------------------------------------------------------------------
// |curl| of one float4 at (z, y, x0). Matches _fdiff (dup-last forward diff).
__device__ __forceinline__ float4 curl4_at(const float* __restrict__ u,
                                           const float* __restrict__ vv,
                                           const float* __restrict__ w,
                                           int z, int y, int x0, int xq) {
    size_t s = ((size_t)z << 14) | ((size_t)y << 7) | (size_t)x0;
    int dy = (y < 127) ? 128 : -128;
    int dz = (z < 127) ? 16384 : -16384;
    float sy = (y < 127) ? 1.f : -1.f;
    float sz = (z < 127) ? 1.f : -1.f;
    int dxp = (xq < 31) ? 4 : 0;

    const float4 wc  = *(const float4*)(w  + s);
    const float4 wyn = *(const float4*)(w  + s + dy);
    const float4 vc  = *(const float4*)(vv + s);
    const float4 vzn = *(const float4*)(vv + s + dz);
    const float4 uc  = *(const float4*)(u  + s);
    const float4 uzn = *(const float4*)(u  + s + dz);
    const float4 uyn = *(const float4*)(u  + s + dy);
    const float  wxp = w [s + 3 + dxp];
    const float  vxp = vv[s + 3 + dxp];

    float wca[4] = {wc.x, wc.y, wc.z, wc.w};
    float vca[4] = {vc.x, vc.y, vc.z, vc.w};
    float wya[4] = {wyn.x, wyn.y, wyn.z, wyn.w};
    float vza[4] = {vzn.x, vzn.y, vzn.z, vzn.w};
    float uca[4] = {uc.x, uc.y, uc.z, uc.w};
    float uza[4] = {uzn.x, uzn.y, uzn.z, uzn.w};
    float uya[4] = {uyn.x, uyn.y, uyn.z, uyn.w};
    float wsh[4] = {wc.y, wc.z, wc.w, wxp};
    float vsh[4] = {vc.y, vc.z, vc.w, vxp};

    float4 o;
    float* oa = &o.x;
#pragma unroll
    for (int j = 0; j < 4; ++j) {
        int x = x0 + j;
        float fdxw = (x < 127) ? (wsh[j] - wca[j]) : (wca[3] - wca[2]);
        float fdxv = (x < 127) ? (vsh[j] - vca[j]) : (vca[3] - vca[2]);
        float fdyw = sy * (wya[j] - wca[j]);
        float fdyu = sy * (uya[j] - uca[j]);
        float fdzv = sz * (vza[j] - vca[j]);
        float fdzu = sz * (uza[j] - uca[j]);
        float cu = fdyw - fdzv;
        float cv = fdzu - fdxw;
        float cw = fdxv - fdyu;
        oa[j] = sqrtf(cu * cu + cv * cv + cw * cw);
    }
    return o;
}

// Fused |curl(v)| + z-smooth — ACCUMULATOR STREAMING (no 14-deep ring).
// Each curl plane value is scattered into the <=7 output accumulators it
// feeds. Live regs ~90: 8 acc + 1 curl + loads in flight. No spill.
__global__ __launch_bounds__(256, 2)
void curl_zsmooth4_kernel(const float* __restrict__ v, float* __restrict__ vn,
                          GaussW gw) {
    int idx = blockIdx.x * blockDim.x + threadIdx.x;  // 2^18 threads
    int xq = idx & 31;
    int y  = (idx >> 5) & 127;
    int zb = (idx >> 12) & 15;
    int n  = idx >> 16;
    int x0 = xq << 2;
    int z0 = zb * 8;
    const float* u  = v + (size_t)n * 3 * VOX;
    const float* vv = u + VOX;
    const float* w  = vv + VOX;

    float4 acc[8];
#pragma unroll
    for (int i = 0; i < 8; ++i) acc[i] = f4zero();

#pragma unroll
    for (int jj = 0; jj < 14; ++jj) {
        int zz = z0 - 3 + jj;
        if (zz >= 0 && zz < 128) {          // wave-uniform (zb uniform in wave)
            float4 c = curl4_at(u, vv, w, zz, y, x0, xq);
#pragma unroll
            for (int i = 0; i < 8; ++i) {
                int k = jj - i;             // tap index feeding output i
                if (k >= 0 && k < 7) {
                    float wk = gw.w[k];
                    acc[i].x += wk * c.x;
                    acc[i].y += wk * c.y;
                    acc[i].z += wk * c.z;
                    acc[i].w += wk * c.w;
                }
            }
        }
    }

    size_t obase = ((size_t)n << 21) | ((size_t)y << 7) | (size_t)x0;
#pragma unroll
    for (int i = 0; i < 8; ++i)
        *(float4*)(vn + (obase | ((size_t)(z0 + i) << 14))) = acc[i];
}

// ---------------------------------------------------------------------------
// Fused y-conv + x-conv for one (n, z, y-quarter) slab. float4 throughout.
// LDS 36 KB -> 4 blocks/CU.
__global__ void yx_smooth4_kernel(const float* __restrict__ in, float* __restrict__ out,
                                  GaussW gw) {
    __shared__ float in_t[38][128];    // y0-3 .. y0+34
    __shared__ float mid[32][136];     // col = x+4; cols 0-3 & 132-135 zero halo

    int b  = blockIdx.x;               // NB*DD*4 = 2048
    int yq = b & 3;
    int z  = (b >> 2) & 127;
    int n  = b >> 9;
    int y0 = yq * 32;
    size_t slice = (((size_t)n << 7) | (size_t)z) << 14;
    int tid = threadIdx.x;

    for (int j = tid; j < 38 * 32; j += 256) {
        int r  = j >> 5;
        int c4 = (j & 31) << 2;
        int gy = y0 - 3 + r;
        float4 val = (gy >= 0 && gy < 128)
                   ? *(const float4*)(in + slice + ((size_t)gy << 7) + c4)
                   : f4zero();
        *(float4*)&in_t[r][c4] = val;
    }
    __syncthreads();

    if (tid < 32) {
        *(float4*)&mid[tid][0]   = f4zero();
        *(float4*)&mid[tid][132] = f4zero();
    }
    for (int j = tid; j < 32 * 32; j += 256) {
        int yo = j >> 5;
        int c4 = (j & 31) << 2;
        float4 a = f4zero();
#pragma unroll
        for (int k = 0; k < 7; ++k) {
            float wk = gw.w[k];
            float4 t = *(const float4*)&in_t[yo + k][c4];
            a.x += wk * t.x; a.y += wk * t.y; a.z += wk * t.z; a.w += wk * t.w;
        }
        *(float4*)&mid[yo][c4 + 4] = a;
    }
    __syncthreads();

    for (int j = tid; j < 32 * 32; j += 256) {
        int yo  = j >> 5;
        int x0c = (j & 31) << 2;
        float4 m0 = *(const float4*)&mid[yo][x0c];
        float4 m1 = *(const float4*)&mid[yo][x0c + 4];
        float4 m2 = *(const float4*)&mid[yo][x0c + 8];
        float wdw[12] = {m0.x, m0.y, m0.z, m0.w,
                         m1.x, m1.y, m1.z, m1.w,
                         m2.x, m2.y, m2.z, m2.w};
        float o[4];
#pragma unroll
        for (int j2 = 0; j2 < 4; ++j2) {
            float acc = 0.f;
#pragma unroll
            for (int k = 0; k < 7; ++k) acc += gw.w[k] * wdw[j2 + 1 + k];
            o[j2] = acc;
        }
        *(float4*)(out + slice + ((size_t)(y0 + yo) << 7) + x0c) =
            make_float4(o[0], o[1], o[2], o[3]);
    }
}

// ---------------------------------------------------------------------------
// Render: per (n,y,x) column, flip z, cumsum -> transmittance, trapezoid, clip.
// __expf is safe: absmax identical (0.015625) with expf and __expf (R4-R6).
#define RBATCH 16
__global__ void render_kernel(const float* __restrict__ ds, const float* __restrict__ vn,
                              float* __restrict__ out) {
    int idx = blockIdx.x * blockDim.x + threadIdx.x;  // NB*HH*WW = 65536
    if (idx >= NB * HH * WW) return;
    int x = idx & 127;
    int y = (idx >> 7) & 127;
    int n = idx >> 14;
    size_t volbase = (size_t)n * VOX + ((size_t)y << 7) + x;

    float xacc = 0.f, acc = 0.f, tp = 0.f, vp = 0.f;
    for (int b = 0; b < 128 / RBATCH; ++b) {
        float rds[RBATCH], rvn[RBATCH];
#pragma unroll
        for (int i = 0; i < RBATCH; ++i) {
            int z = 127 - (b * RBATCH + i);
            size_t off = volbase + ((size_t)z << 14);
            rds[i] = ds[off];
            rvn[i] = vn[off];
        }
#pragma unroll
        for (int i = 0; i < RBATCH; ++i) {
            int k = b * RBATCH + i;
            xacc += rds[i];
            float xc = 20.f * xacc;
            float tk = (xc + 1.f) * __expf(-xc);
            float vk = rvn[i];
            if (k == 0) acc = (1.f - tk) * vk;
            else        acc += (tp - tk) * (vp + vk) * 0.5f;
            tp = tk; vp = vk;
        }
    }
    out[idx] = fminf(fmaxf(acc, 0.f), 1.f);
}

// ---------------------------------------------------------------------------
extern "C" void kernel_launch(void* const* d_in, const int* in_sizes, int n_in,
                              void* d_out, int out_size, void* d_ws, size_t ws_size,
                              hipStream_t stream) {
    const float* d = (const float*)d_in[0];   // (4,1,128,128,128)
    const float* v = (const float*)d_in[1];   // (4,3,128,128,128)
    float* out = (float*)d_out;               // (4,1,128,128)

    GaussW gw;
    {
        double g[7], s = 0.0;
        for (int i = 0; i < 7; ++i) {
            double t = (i - 3) / 1.6;
            g[i] = exp(-t * t / 2.0);
            s += g[i];
        }
        for (int i = 0; i < 7; ++i) gw.w[i] = (float)(g[i] / s);
    }

    float* ws0 = (float*)d_ws;        // ds final
    float* ws1 = ws0 + NVOX;          // intermediates
    float* ws2 = ws1 + NVOX;          // vn final

    const int TB = 256;

    // vn chain: fused curl+z-smooth (accumulator streaming), then fused y+x
    curl_zsmooth4_kernel<<<(1 << 18) / TB, TB, 0, stream>>>(v, ws1, gw);
    yx_smooth4_kernel<<<NB * DD * 4, TB, 0, stream>>>(ws1, ws2, gw);

    // ds chain: z-smooth (register ring), then fused y+x
    smooth_roll4_kernel<14><<<(NVOX / 32) / TB, TB, 0, stream>>>(d, ws1, gw);
    yx_smooth4_kernel<<<NB * DD * 4, TB, 0, stream>>>(ws1, ws0, gw);

    // final render reduction
    render_kernel<<<(NB * HH * WW) / TB, TB, 0, stream>>>(ws0, ws2, out);
}

// Round 8
// 212.197 us; speedup vs baseline: 1.3582x; 1.1231x over previous
//
#include <hip/hip_runtime.h>
#include <math.h>

#define NB 4
#define DD 128
#define HH 128
#define WW 128
#define VOX (DD*HH*WW)          // 2097152 = 2^21
#define NVOX (NB*VOX)           // 8388608

struct GaussW { float w[7]; };

__device__ __forceinline__ float4 f4zero() { float4 z; z.x = z.y = z.z = z.w = 0.f; return z; }

// ---------------------------------------------------------------------------
// |curl(v)| vectorized x4 along x (R5's proven kernel). v layout (N,3,D,H,W).
__global__ void curl4_kernel(const float* __restrict__ v, float* __restrict__ vn) {
    int idx = blockIdx.x * blockDim.x + threadIdx.x;  // NVOX/4
    int xq = idx & 31;
    int y  = (idx >> 5) & 127;
    int z  = (idx >> 12) & 127;
    int n  = idx >> 19;
    int x0 = xq << 2;
    const float* u  = v + (size_t)n * 3 * VOX;
    const float* vv = u + VOX;
    const float* w  = vv + VOX;
    size_t s = ((size_t)z << 14) | ((size_t)y << 7) | (size_t)x0;

    int dy = (y < 127) ? 128 : -128;
    int dz = (z < 127) ? 16384 : -16384;
    float sy = (y < 127) ? 1.f : -1.f;
    float sz = (z < 127) ? 1.f : -1.f;
    int dxp = (xq < 31) ? 4 : 0;

    const float4 wc  = *(const float4*)(w  + s);
    const float4 wyn = *(const float4*)(w  + s + dy);
    const float4 vc  = *(const float4*)(vv + s);
    const float4 vzn = *(const float4*)(vv + s + dz);
    const float4 uc  = *(const float4*)(u  + s);
    const float4 uzn = *(const float4*)(u  + s + dz);
    const float4 uyn = *(const float4*)(u  + s + dy);
    const float  wxp = w [s + 3 + dxp];
    const float  vxp = vv[s + 3 + dxp];

    float wca[4] = {wc.x, wc.y, wc.z, wc.w};
    float vca[4] = {vc.x, vc.y, vc.z, vc.w};
    float wya[4] = {wyn.x, wyn.y, wyn.z, wyn.w};
    float vza[4] = {vzn.x, vzn.y, vzn.z, vzn.w};
    float uca[4] = {uc.x, uc.y, uc.z, uc.w};
    float uza[4] = {uzn.x, uzn.y, uzn.z, uzn.w};
    float uya[4] = {uyn.x, uyn.y, uyn.z, uyn.w};
    float wsh[4] = {wc.y, wc.z, wc.w, wxp};
    float vsh[4] = {vc.y, vc.z, vc.w, vxp};

    float4 o;
    float* oa = &o.x;
#pragma unroll
    for (int j = 0; j < 4; ++j) {
        int x = x0 + j;
        float fdxw = (x < 127) ? (wsh[j] - wca[j]) : (wca[3] - wca[2]);
        float fdxv = (x < 127) ? (vsh[j] - vca[j]) : (vca[3] - vca[2]);
        float fdyw = sy * (wya[j] - wca[j]);
        float fdyu = sy * (uya[j] - uca[j]);
        float fdzv = sz * (vza[j] - vca[j]);
        float fdzu = sz * (uza[j] - uca[j]);
        float cu = fdyw - fdzv;
        float cv = fdzu - fdxw;
        float cw = fdxv - fdyu;
        oa[j] = sqrtf(cu * cu + cv * cv + cw * cw);
    }
    *(float4*)(vn + ((size_t)n * VOX) + s) = o;
}

// ---------------------------------------------------------------------------
// Fused y-conv + x-conv for one (n, z, y-quarter) slab of ONE OF TWO fields:
// blocks [0, 2048) process inA->outA (d), blocks [2048, 4096) inB->outB (curl).
// LDS 36 KB -> 4 blocks/CU.
__global__ void yx_smooth4_dual_kernel(const float* __restrict__ inA, float* __restrict__ outA,
                                       const float* __restrict__ inB, float* __restrict__ outB,
                                       GaussW gw) {
    __shared__ float in_t[38][128];    // y0-3 .. y0+34
    __shared__ float mid[32][136];     // col = x+4; cols 0-3 & 132-135 zero halo

    int bb = blockIdx.x;               // 2 * NB*DD*4 = 4096
    const float* in  = (bb < 2048) ? inA  : inB;
    float*       out = (bb < 2048) ? outA : outB;
    int b  = bb & 2047;
    int yq = b & 3;
    int z  = (b >> 2) & 127;
    int n  = b >> 9;
    int y0 = yq * 32;
    size_t slice = (((size_t)n << 7) | (size_t)z) << 14;
    int tid = threadIdx.x;

    for (int j = tid; j < 38 * 32; j += 256) {
        int r  = j >> 5;
        int c4 = (j & 31) << 2;
        int gy = y0 - 3 + r;
        float4 val = (gy >= 0 && gy < 128)
                   ? *(const float4*)(in + slice + ((size_t)gy << 7) + c4)
                   : f4zero();
        *(float4*)&in_t[r][c4] = val;
    }
    __syncthreads();

    if (tid < 32) {
        *(float4*)&mid[tid][0]   = f4zero();
        *(float4*)&mid[tid][132] = f4zero();
    }
    for (int j = tid; j < 32 * 32; j += 256) {
        int yo = j >> 5;
        int c4 = (j & 31) << 2;
        float4 a = f4zero();
#pragma unroll
        for (int k = 0; k < 7; ++k) {
            float wk = gw.w[k];
            float4 t = *(const float4*)&in_t[yo + k][c4];
            a.x += wk * t.x; a.y += wk * t.y; a.z += wk * t.z; a.w += wk * t.w;
        }
        *(float4*)&mid[yo][c4 + 4] = a;
    }
    __syncthreads();

    for (int j = tid; j < 32 * 32; j += 256) {
        int yo  = j >> 5;
        int x0c = (j & 31) << 2;
        float4 m0 = *(const float4*)&mid[yo][x0c];
        float4 m1 = *(const float4*)&mid[yo][x0c + 4];
        float4 m2 = *(const float4*)&mid[yo][x0c + 8];
        float wdw[12] = {m0.x, m0.y, m0.z, m0.w,
                         m1.x, m1.y, m1.z, m1.w,
                         m2.x, m2.y, m2.z, m2.w};
        float o[4];
#pragma unroll
        for (int j2 = 0; j2 < 4; ++j2) {
            float acc = 0.f;
#pragma unroll
            for (int k = 0; k < 7; ++k) acc += gw.w[k] * wdw[j2 + 1 + k];
            o[j2] = acc;
        }
        *(float4*)(out + slice + ((size_t)(y0 + yo) << 7) + x0c) =
            make_float4(o[0], o[1], o[2], o[3]);
    }
}

// ---------------------------------------------------------------------------
// Render with ON-THE-FLY z-smooth of both fields. P = yx-smoothed d,
// Q = yx-smoothed |curl|. The Gaussian is symmetric, so in flipped-z
// coordinates (j = 127-z) the 7-tap zero-padded conv is unchanged:
//   ds_f[j] = sum_k w[k] * pf[j-3+k],  pf[j] = P[z=127-j], pad 0.
// Then cumsum ds_f, transmittance, trapezoid against vn_f, clip.
#define RBATCH 16
__global__ __launch_bounds__(256, 2)
void render_zs_kernel(const float* __restrict__ P, const float* __restrict__ Q,
                      float* __restrict__ out, GaussW gw) {
    int idx = blockIdx.x * blockDim.x + threadIdx.x;  // NB*HH*WW = 65536
    if (idx >= NB * HH * WW) return;
    int x = idx & 127;
    int y = (idx >> 7) & 127;
    int n = idx >> 14;
    size_t volbase = (size_t)n * VOX + ((size_t)y << 7) + x;

    // carry = pf/qf[j0-3 .. j0+2] entering each batch
    float pc[6], qc[6];
#pragma unroll
    for (int t = 0; t < 3; ++t) { pc[t] = 0.f; qc[t] = 0.f; }
#pragma unroll
    for (int t = 3; t < 6; ++t) {
        int j = t - 3;                        // 0,1,2
        size_t off = volbase + ((size_t)(127 - j) << 14);
        pc[t] = P[off];
        qc[t] = Q[off];
    }

    float xacc = 0.f, acc = 0.f, tp = 0.f, vp = 0.f;
    for (int b = 0; b < 128 / RBATCH; ++b) {
        int j0 = b * RBATCH;
        float pw[RBATCH + 6], qw[RBATCH + 6];
#pragma unroll
        for (int t = 0; t < 6; ++t) { pw[t] = pc[t]; qw[t] = qc[t]; }
#pragma unroll
        for (int i = 0; i < RBATCH; ++i) {
            int j = j0 + 3 + i;               // pf[j0+3 .. j0+18]
            if (j <= 127) {
                size_t off = volbase + ((size_t)(127 - j) << 14);
                pw[6 + i] = P[off];
                qw[6 + i] = Q[off];
            } else {
                pw[6 + i] = 0.f;
                qw[6 + i] = 0.f;
            }
        }
#pragma unroll
        for (int i = 0; i < RBATCH; ++i) {
            float dsf = 0.f, vnf = 0.f;
#pragma unroll
            for (int k = 0; k < 7; ++k) {
                float wk = gw.w[k];
                dsf += wk * pw[i + k];        // pf[j0+i-3+k]
                vnf += wk * qw[i + k];
            }
            xacc += dsf;
            float xc = 20.f * xacc;
            float tk = (xc + 1.f) * __expf(-xc);
            if (j0 + i == 0) acc = (1.f - tk) * vnf;
            else             acc += (tp - tk) * (vp + vnf) * 0.5f;
            tp = tk; vp = vnf;
        }
#pragma unroll
        for (int t = 0; t < 6; ++t) { pc[t] = pw[RBATCH + t]; qc[t] = qw[RBATCH + t]; }
    }
    out[idx] = fminf(fmaxf(acc, 0.f), 1.f);
}

// ---------------------------------------------------------------------------
extern "C" void kernel_launch(void* const* d_in, const int* in_sizes, int n_in,
                              void* d_out, int out_size, void* d_ws, size_t ws_size,
                              hipStream_t stream) {
    const float* d = (const float*)d_in[0];   // (4,1,128,128,128)
    const float* v = (const float*)d_in[1];   // (4,3,128,128,128)
    float* out = (float*)d_out;               // (4,1,128,128)

    GaussW gw;
    {
        double g[7], s = 0.0;
        for (int i = 0; i < 7; ++i) {
            double t = (i - 3) / 1.6;
            g[i] = exp(-t * t / 2.0);
            s += g[i];
        }
        for (int i = 0; i < 7; ++i) gw.w[i] = (float)(g[i] / s);
    }

    float* ws0 = (float*)d_ws;        // P = yx-smoothed d
    float* ws1 = ws0 + NVOX;          // raw |curl|
    float* ws2 = ws1 + NVOX;          // Q = yx-smoothed |curl|

    const int TB = 256;

    // 1) raw |curl(v)|
    curl4_kernel<<<(NVOX / 4) / TB, TB, 0, stream>>>(v, ws1);

    // 2) yx-smooth both fields in one dual-grid launch
    yx_smooth4_dual_kernel<<<2 * NB * DD * 4, TB, 0, stream>>>(d, ws0, ws1, ws2, gw);

    // 3) render with on-the-fly z-smooth of both fields
    render_zs_kernel<<<(NB * HH * WW) / TB, TB, 0, stream>>>(ws0, ws2, out, gw);
}

// Round 9
// 202.810 us; speedup vs baseline: 1.4210x; 1.0463x over previous
//
#include <hip/hip_runtime.h>
#include <math.h>

#define NB 4
#define DD 128
#define HH 128
#define WW 128
#define VOX (DD*HH*WW)          // 2097152 = 2^21
#define NVOX (NB*VOX)           // 8388608

struct GaussW { float w[7]; };

__device__ __forceinline__ float4 f4zero() { float4 z; z.x = z.y = z.z = z.w = 0.f; return z; }

// ---------------------------------------------------------------------------
// |curl| of one float4 at (z, y, x0). Matches _fdiff (dup-last forward diff).
__device__ __forceinline__ float4 curl4_at(const float* __restrict__ u,
                                           const float* __restrict__ vv,
                                           const float* __restrict__ w,
                                           int z, int y, int x0) {
    int xq = x0 >> 2;
    size_t s = ((size_t)z << 14) | ((size_t)y << 7) | (size_t)x0;
    int dy = (y < 127) ? 128 : -128;
    int dz = (z < 127) ? 16384 : -16384;
    float sy = (y < 127) ? 1.f : -1.f;
    float sz = (z < 127) ? 1.f : -1.f;
    int dxp = (xq < 31) ? 4 : 0;

    const float4 wc  = *(const float4*)(w  + s);
    const float4 wyn = *(const float4*)(w  + s + dy);
    const float4 vc  = *(const float4*)(vv + s);
    const float4 vzn = *(const float4*)(vv + s + dz);
    const float4 uc  = *(const float4*)(u  + s);
    const float4 uzn = *(const float4*)(u  + s + dz);
    const float4 uyn = *(const float4*)(u  + s + dy);
    const float  wxp = w [s + 3 + dxp];
    const float  vxp = vv[s + 3 + dxp];

    float wca[4] = {wc.x, wc.y, wc.z, wc.w};
    float vca[4] = {vc.x, vc.y, vc.z, vc.w};
    float wya[4] = {wyn.x, wyn.y, wyn.z, wyn.w};
    float vza[4] = {vzn.x, vzn.y, vzn.z, vzn.w};
    float uca[4] = {uc.x, uc.y, uc.z, uc.w};
    float uza[4] = {uzn.x, uzn.y, uzn.z, uzn.w};
    float uya[4] = {uyn.x, uyn.y, uyn.z, uyn.w};
    float wsh[4] = {wc.y, wc.z, wc.w, wxp};
    float vsh[4] = {vc.y, vc.z, vc.w, vxp};

    float4 o;
    float* oa = &o.x;
#pragma unroll
    for (int j = 0; j < 4; ++j) {
        int x = x0 + j;
        float fdxw = (x < 127) ? (wsh[j] - wca[j]) : (wca[3] - wca[2]);
        float fdxv = (x < 127) ? (vsh[j] - vca[j]) : (vca[3] - vca[2]);
        float fdyw = sy * (wya[j] - wca[j]);
        float fdyu = sy * (uya[j] - uca[j]);
        float fdzv = sz * (vza[j] - vca[j]);
        float fdzu = sz * (uza[j] - uca[j]);
        float cu = fdyw - fdzv;
        float cv = fdzu - fdxw;
        float cw = fdxv - fdyu;
        oa[j] = sqrtf(cu * cu + cv * cv + cw * cw);
    }
    return o;
}

// ---------------------------------------------------------------------------
// Dual-mode fused kernel, one (n, z, y-quarter) slab per block:
//   blocks [0,2048):    stage d rows in LDS            -> y-conv -> x-conv -> P
//   blocks [2048,4096): compute |curl(v)| rows into LDS -> y-conv -> x-conv -> Q
// LDS 36 KB, launch_bounds(256,4) -> 4 blocks/CU (matches the LDS limit).
__global__ __launch_bounds__(256, 4)
void yx_curl_dual_kernel(const float* __restrict__ dIn, float* __restrict__ P,
                         const float* __restrict__ v,   float* __restrict__ Q,
                         GaussW gw) {
    __shared__ float in_t[38][128];    // field rows y0-3 .. y0+34 of slice z
    __shared__ float mid[32][136];     // col = x+4; cols 0-3 & 132-135 zero halo

    int bb = blockIdx.x;               // 4096
    bool isCurl = (bb >= 2048);
    int b  = bb & 2047;
    int yq = b & 3;
    int z  = (b >> 2) & 127;
    int n  = b >> 9;
    int y0 = yq * 32;
    size_t slice = (((size_t)n << 7) | (size_t)z) << 14;
    int tid = threadIdx.x;

    if (!isCurl) {
        // stage d rows (float4, zero-padded in y)
        for (int j = tid; j < 38 * 32; j += 256) {
            int r  = j >> 5;
            int c4 = (j & 31) << 2;
            int gy = y0 - 3 + r;
            float4 val = (gy >= 0 && gy < 128)
                       ? *(const float4*)(dIn + slice + ((size_t)gy << 7) + c4)
                       : f4zero();
            *(float4*)&in_t[r][c4] = val;
        }
    } else {
        // compute |curl| rows directly from v into LDS
        const float* u  = v + (size_t)n * 3 * VOX;
        const float* vv = u + VOX;
        const float* w  = vv + VOX;
        for (int j = tid; j < 38 * 32; j += 256) {
            int r  = j >> 5;
            int c4 = (j & 31) << 2;
            int gy = y0 - 3 + r;
            float4 val = (gy >= 0 && gy < 128)
                       ? curl4_at(u, vv, w, z, gy, c4)
                       : f4zero();
            *(float4*)&in_t[r][c4] = val;
        }
    }
    __syncthreads();

    if (tid < 32) {
        *(float4*)&mid[tid][0]   = f4zero();
        *(float4*)&mid[tid][132] = f4zero();
    }
    // y-conv -> mid
    for (int j = tid; j < 32 * 32; j += 256) {
        int yo = j >> 5;
        int c4 = (j & 31) << 2;
        float4 a = f4zero();
#pragma unroll
        for (int k = 0; k < 7; ++k) {
            float wk = gw.w[k];
            float4 t = *(const float4*)&in_t[yo + k][c4];
            a.x += wk * t.x; a.y += wk * t.y; a.z += wk * t.z; a.w += wk * t.w;
        }
        *(float4*)&mid[yo][c4 + 4] = a;
    }
    __syncthreads();

    // x-conv -> global
    float* out = isCurl ? Q : P;
    for (int j = tid; j < 32 * 32; j += 256) {
        int yo  = j >> 5;
        int x0c = (j & 31) << 2;
        float4 m0 = *(const float4*)&mid[yo][x0c];
        float4 m1 = *(const float4*)&mid[yo][x0c + 4];
        float4 m2 = *(const float4*)&mid[yo][x0c + 8];
        float wdw[12] = {m0.x, m0.y, m0.z, m0.w,
                         m1.x, m1.y, m1.z, m1.w,
                         m2.x, m2.y, m2.z, m2.w};
        float o[4];
#pragma unroll
        for (int j2 = 0; j2 < 4; ++j2) {
            float acc = 0.f;
#pragma unroll
            for (int k = 0; k < 7; ++k) acc += gw.w[k] * wdw[j2 + 1 + k];
            o[j2] = acc;
        }
        *(float4*)(out + slice + ((size_t)(y0 + yo) << 7) + x0c) =
            make_float4(o[0], o[1], o[2], o[3]);
    }
}

// ---------------------------------------------------------------------------
// Render with on-the-fly z-smooth of both fields (Gaussian symmetric =>
// conv commutes with the z-flip; zero padding preserved in flipped coords).
#define RBATCH 16
__global__ __launch_bounds__(256, 2)
void render_zs_kernel(const float* __restrict__ P, const float* __restrict__ Q,
                      float* __restrict__ out, GaussW gw) {
    int idx = blockIdx.x * blockDim.x + threadIdx.x;  // NB*HH*WW = 65536
    if (idx >= NB * HH * WW) return;
    int x = idx & 127;
    int y = (idx >> 7) & 127;
    int n = idx >> 14;
    size_t volbase = (size_t)n * VOX + ((size_t)y << 7) + x;

    float pc[6], qc[6];
#pragma unroll
    for (int t = 0; t < 3; ++t) { pc[t] = 0.f; qc[t] = 0.f; }
#pragma unroll
    for (int t = 3; t < 6; ++t) {
        int j = t - 3;
        size_t off = volbase + ((size_t)(127 - j) << 14);
        pc[t] = P[off];
        qc[t] = Q[off];
    }

    float xacc = 0.f, acc = 0.f, tp = 0.f, vp = 0.f;
    for (int b = 0; b < 128 / RBATCH; ++b) {
        int j0 = b * RBATCH;
        float pw[RBATCH + 6], qw[RBATCH + 6];
#pragma unroll
        for (int t = 0; t < 6; ++t) { pw[t] = pc[t]; qw[t] = qc[t]; }
#pragma unroll
        for (int i = 0; i < RBATCH; ++i) {
            int j = j0 + 3 + i;
            if (j <= 127) {
                size_t off = volbase + ((size_t)(127 - j) << 14);
                pw[6 + i] = P[off];
                qw[6 + i] = Q[off];
            } else {
                pw[6 + i] = 0.f;
                qw[6 + i] = 0.f;
            }
        }
#pragma unroll
        for (int i = 0; i < RBATCH; ++i) {
            float dsf = 0.f, vnf = 0.f;
#pragma unroll
            for (int k = 0; k < 7; ++k) {
                float wk = gw.w[k];
                dsf += wk * pw[i + k];
                vnf += wk * qw[i + k];
            }
            xacc += dsf;
            float xc = 20.f * xacc;
            float tk = (xc + 1.f) * __expf(-xc);
            if (j0 + i == 0) acc = (1.f - tk) * vnf;
            else             acc += (tp - tk) * (vp + vnf) * 0.5f;
            tp = tk; vp = vnf;
        }
#pragma unroll
        for (int t = 0; t < 6; ++t) { pc[t] = pw[RBATCH + t]; qc[t] = qw[RBATCH + t]; }
    }
    out[idx] = fminf(fmaxf(acc, 0.f), 1.f);
}

// ---------------------------------------------------------------------------
extern "C" void kernel_launch(void* const* d_in, const int* in_sizes, int n_in,
                              void* d_out, int out_size, void* d_ws, size_t ws_size,
                              hipStream_t stream) {
    const float* d = (const float*)d_in[0];   // (4,1,128,128,128)
    const float* v = (const float*)d_in[1];   // (4,3,128,128,128)
    float* out = (float*)d_out;               // (4,1,128,128)

    GaussW gw;
    {
        double g[7], s = 0.0;
        for (int i = 0; i < 7; ++i) {
            double t = (i - 3) / 1.6;
            g[i] = exp(-t * t / 2.0);
            s += g[i];
        }
        for (int i = 0; i < 7; ++i) gw.w[i] = (float)(g[i] / s);
    }

    float* ws0 = (float*)d_ws;        // P = yx-smoothed d
    float* ws1 = ws0 + NVOX;          // Q = yx-smoothed |curl|

    const int TB = 256;

    // 1) fused: d yx-smooth (blocks 0-2047) + curl-on-the-fly yx-smooth (2048-4095)
    yx_curl_dual_kernel<<<2 * NB * DD * 4, TB, 0, stream>>>(d, ws0, v, ws1, gw);

    // 2) render with on-the-fly z-smooth of both fields
    render_zs_kernel<<<(NB * HH * WW) / TB, TB, 0, stream>>>(ws0, ws1, out, gw);
}